// Round 3
// 13416.534 us; speedup vs baseline: 1.5064x; 1.5064x over previous
//
#include <hip/hip_runtime.h>
#include <hip/hip_bf16.h>

typedef __bf16 bf16x8 __attribute__((ext_vector_type(8)));
typedef float floatx4 __attribute__((ext_vector_type(4)));

#define HID 1024
#define HH (1024*1024)
#define SEQ 512
#define NB 32768  /* 32*1024 state elements */
#define NBLK 256

__device__ __forceinline__ float bf2f(unsigned short u) {
  union { unsigned int i; float f; } v; v.i = ((unsigned int)u) << 16; return v.f;
}
__device__ __forceinline__ unsigned short f2bf(float f) {
  union { float f; unsigned int i; } v; v.f = f;
  unsigned int i = v.i;
  return (unsigned short)((i + 0x7fffu + ((i >> 16) & 1u)) >> 16);
}
__device__ __forceinline__ float ldflag(const void* p, long i, int flag) {
  return flag ? ((const float*)p)[i] : bf2f(((const unsigned short*)p)[i]);
}
__device__ __forceinline__ float sigmoidf_(float x) { return 1.0f / (1.0f + __expf(-x)); }

// ---- write-through stores (sc0 sc1). Purpose: keep L2 clean so the release
// fence's buffer_wbl2 has (near) nothing to write back. Correctness does NOT
// depend on these flags: the agent fences in gbar remain the visibility backstop.
#define GSTH(p_, v_)   asm volatile("global_store_short %0, %1, off sc0 sc1" :: "v"(p_), "v"(v_) : "memory")
#define GSTW(p_, v_)   asm volatile("global_store_dword %0, %1, off sc0 sc1" :: "v"(p_), "v"(v_) : "memory")

__device__ __forceinline__ void outw_wt(void* out, int flag, long idx, float v) {
  if (flag) { GSTW((float*)out + idx, v); }
  else      { GSTH((unsigned short*)out + idx, (unsigned int)f2bf(v)); }
}

// ---- dtype detection: bf16 (flag=0) vs fp32 (flag=1) ----
__global__ void detect_k(const unsigned int* __restrict__ xw, int* __restrict__ flag) {
  unsigned int w = xw[threadIdx.x];
  int e = (w >> 7) & 0xFF;
  int ok = (e >= 100 && e <= 141) ? 1 : 0;
  unsigned long long m = __ballot(ok);
  if (threadIdx.x == 0) *flag = (__popcll(m) >= 36) ? 0 : 1;
}

// ---- fp32 -> bf16 conversion of x, 6 weight tensors, WY (no-op when flag=0) ----
__global__ void convert_k(const float* __restrict__ x,
                          const float* __restrict__ w0, const float* __restrict__ w1,
                          const float* __restrict__ w2, const float* __restrict__ w3,
                          const float* __restrict__ w4, const float* __restrict__ w5,
                          const float* __restrict__ wy,
                          unsigned short* __restrict__ xb, unsigned short* __restrict__ wc,
                          unsigned short* __restrict__ wyc, const int* __restrict__ flag) {
  if (*flag == 0) return;
  const float* Ws[6] = { w0, w1, w2, w3, w4, w5 };
  const long total = 3801088;
  for (long c = (long)blockIdx.x * 256 + threadIdx.x; c < total; c += (long)gridDim.x * 256) {
    long e = c * 8;
    const float* src; unsigned short* dst; long off;
    if (e < 16777216)      { src = x;  dst = xb;  off = e; }
    else if (e < 29360128) { long r = e - 16777216; int wi = (int)(r >> 21);
                             src = Ws[wi]; dst = wc + (long)wi * 2097152; off = r & 2097151; }
    else                   { src = wy; dst = wyc; off = e - 29360128; }
    float4 a = *(const float4*)(src + off);
    float4 b = *(const float4*)(src + off + 4);
    uint4 o;
    o.x = (unsigned)f2bf(a.x) | ((unsigned)f2bf(a.y) << 16);
    o.y = (unsigned)f2bf(a.z) | ((unsigned)f2bf(a.w) << 16);
    o.z = (unsigned)f2bf(b.x) | ((unsigned)f2bf(b.y) << 16);
    o.w = (unsigned)f2bf(b.z) | ((unsigned)f2bf(b.w) << 16);
    *(uint4*)(dst + off) = o;
  }
}

// ---- grid barrier: PROVEN fence-based scheme (round-0 baseline), with the
// single counter split 8 ways (256B-apart lines) to cut IF atomic serialization.
__device__ __forceinline__ void gbar(int* cnt, int target, int blk) {
  __syncthreads();
  if (threadIdx.x == 0) {
    __builtin_amdgcn_fence(__ATOMIC_RELEASE, "agent");
    __hip_atomic_fetch_add(cnt + (blk & 7) * 64, 1, __ATOMIC_RELAXED, __HIP_MEMORY_SCOPE_AGENT);
    int ssum;
    do {
      ssum = 0;
      #pragma unroll
      for (int i = 0; i < 8; ++i)
        ssum += __hip_atomic_load(cnt + i * 64, __ATOMIC_RELAXED, __HIP_MEMORY_SCOPE_AGENT);
      if (ssum < target) __builtin_amdgcn_s_sleep(1);
    } while (ssum < target);
    __builtin_amdgcn_fence(__ATOMIC_ACQUIRE, "agent");
  }
  __syncthreads();
}

// ---- stage a (W,U) pair of 16 rows x K=1024 each into MFMA-frag-ordered LDS ----
// frag layout (ushort idx): ((m*32 + kc)*64 + L)*8, kc=k>>5, L=((k>>3)&3)*16 | row
__device__ __forceinline__ void stage2(unsigned short* dst,
                                       const unsigned short* __restrict__ s0,
                                       const unsigned short* __restrict__ s1,
                                       int n0, int tid) {
  const unsigned short* srcs[2] = { s0, s1 };
  #pragma unroll
  for (int i = 0; i < 16; ++i) {
    int idx = i * 256 + tid;          // 0..4095: 2 matrices x 16 rows x 128 k8
    int m = idx >> 11;
    int rem = idx & 2047;
    int r = rem >> 7, k8 = rem & 127;
    bf16x8 v = *(const bf16x8*)(srcs[m] + (long)(n0 + r) * HID + k8 * 8);
    int kc = k8 >> 2, L = ((k8 & 3) << 4) | r;
    *(bf16x8*)(dst + (((m * 32 + kc) * 64 + L) << 3)) = v;
  }
}
__device__ __forceinline__ void stage1(unsigned short* dst,
                                       const unsigned short* __restrict__ s0,
                                       int n0, int tid) {
  #pragma unroll
  for (int i = 0; i < 8; ++i) {
    int idx = i * 256 + tid;          // 0..2047
    int r = idx >> 7, k8 = idx & 127;
    bf16x8 v = *(const bf16x8*)(s0 + (long)(n0 + r) * HID + k8 * 8);
    int kc = k8 >> 2, L = ((k8 & 3) << 4) | r;
    *(bf16x8*)(dst + ((kc * 64 + L) << 3)) = v;
  }
}

// ---- per-wave GEMM: A from global (pre-offset), W from frag-ordered LDS ----
__device__ __forceinline__ floatx4 gpair(const unsigned short* __restrict__ a1,
                                         const unsigned short* __restrict__ a2,
                                         const unsigned short* sW, int khalf, int lane) {
  floatx4 acc = {0.f, 0.f, 0.f, 0.f};
  const unsigned short* w1 = sW + (((khalf * 16) * 64 + lane) << 3);
  const unsigned short* w2 = sW + (((32 + khalf * 16) * 64 + lane) << 3);
  #pragma unroll
  for (int j = 0; j < 16; ++j)
    acc = __builtin_amdgcn_mfma_f32_16x16x32_bf16(*(const bf16x8*)(a1 + j * 32),
                                                  *(const bf16x8*)(w1 + j * 512), acc, 0, 0, 0);
  #pragma unroll
  for (int j = 0; j < 16; ++j)
    acc = __builtin_amdgcn_mfma_f32_16x16x32_bf16(*(const bf16x8*)(a2 + j * 32),
                                                  *(const bf16x8*)(w2 + j * 512), acc, 0, 0, 0);
  return acc;
}
__device__ __forceinline__ floatx4 gsingle(const unsigned short* __restrict__ a,
                                           const unsigned short* sW, int khalf, int lane) {
  floatx4 acc = {0.f, 0.f, 0.f, 0.f};
  const unsigned short* w = sW + (((khalf * 16) * 64 + lane) << 3);
  #pragma unroll
  for (int j = 0; j < 16; ++j)
    acc = __builtin_amdgcn_mfma_f32_16x16x32_bf16(*(const bf16x8*)(a + j * 32),
                                                  *(const bf16x8*)(w + j * 512), acc, 0, 0, 0);
  return acc;
}

// Persistent GRU, 256 blocks x 256 threads, LDS-resident weights.
// P roles (blk>>6): 0=z0, 1=r0, 2=z1, 3=r1; 16 cols each ((blk&63)*16).
// Q roles: 0=g0, 1=g1, 2=Y (16 cols, (blk-128)*16), 3=idle.
__global__ void __launch_bounds__(256, 1) gru2(
    const void* __restrict__ x, const void* __restrict__ h0i,
    const void* __restrict__ Wxz, const void* __restrict__ Wxr, const void* __restrict__ Wxg,
    const void* __restrict__ Whz, const void* __restrict__ Whr, const void* __restrict__ Whg,
    const void* __restrict__ bhz, const void* __restrict__ bhr, const void* __restrict__ bhg,
    const void* __restrict__ WY, const void* __restrict__ bY,
    void* __restrict__ out, const int* __restrict__ flagp, int* __restrict__ barCnt,
    const unsigned short* __restrict__ xb, const unsigned short* __restrict__ wcv,
    const unsigned short* __restrict__ wyc,
    float* __restrict__ h0f, float* __restrict__ h1f,
    float* __restrict__ z0f, float* __restrict__ z1f,
    unsigned short* __restrict__ h0b, unsigned short* __restrict__ h1b,
    unsigned short* __restrict__ rh0, unsigned short* __restrict__ rh1)
{
  extern __shared__ char smem[];
  unsigned short* sWP = (unsigned short*)smem;             // 65536 B
  unsigned short* sWQ = (unsigned short*)(smem + 65536);   // 65536 B
  floatx4* red = (floatx4*)(smem + 131072);                // 4096 B

  const int flag = *flagp;
  const int thr  = threadIdx.x;
  const int wave = thr >> 6;
  const int lane = thr & 63;
  const int l15  = lane & 15;
  const int kq   = (lane >> 4) * 8;
  const int blk  = blockIdx.x;
  const int role = blk >> 6;
  const int c0   = (blk & 63) * 16;

  const unsigned short* xP  = flag ? xb                : (const unsigned short*)x;
  const unsigned short* Wzp = flag ? wcv + 0L*2097152  : (const unsigned short*)Wxz;
  const unsigned short* Wrp = flag ? wcv + 1L*2097152  : (const unsigned short*)Wxr;
  const unsigned short* Wgp = flag ? wcv + 2L*2097152  : (const unsigned short*)Wxg;
  const unsigned short* Uzp = flag ? wcv + 3L*2097152  : (const unsigned short*)Whz;
  const unsigned short* Urp = flag ? wcv + 4L*2097152  : (const unsigned short*)Whr;
  const unsigned short* Ugp = flag ? wcv + 5L*2097152  : (const unsigned short*)Whg;
  const unsigned short* WYp = flag ? wyc               : (const unsigned short*)WY;

  // ---- one-time weight staging into LDS (block-local) ----
  {
    long off = (role >> 1) ? (long)HH : 0;
    const unsigned short* s0 = ((role & 1) ? Wrp : Wzp) + off;
    const unsigned short* s1 = ((role & 1) ? Urp : Uzp) + off;
    stage2(sWP, s0, s1, c0, thr);
  }
  if (blk < 128)      stage2(sWQ, Wgp + (blk >= 64 ? (long)HH : 0),
                             Ugp + (blk >= 64 ? (long)HH : 0), c0, thr);
  else if (blk < 192) stage1(sWQ, WYp, (blk - 128) * 16, thr);

  // ---- init hidden state (h_{-1}) into both parity buffers ----
  {
    int gtid = blk * 256 + thr;          // 0..65535
    int layer = gtid >> 15, i = gtid & 32767;
    float v = ldflag(h0i, (long)layer * NB + i, flag);
    unsigned int b = f2bf(v);
    if (layer == 0) { GSTW(h0f + i, v); GSTH(h0b + i, b); GSTH(h0b + NB + i, b); }
    else            { GSTW(h1f + i, v); GSTH(h1b + i, b); GSTH(h1b + NB + i, b); }
  }
  int bt = 0;
  bt += NBLK; gbar(barCnt, bt, blk);

  for (int s = 0; s < SEQ + 2; ++s) {
    const int pPrev  = ((s + 1) & 1) * NB;  // parity slot of h_{s-1}
    const int pPrev2 = (s & 1) * NB;        // parity slot of h_{s-2}
    const int mt = wave & 1, khalf = wave >> 1;
    const int m = mt * 16 + l15;
    const int aoff = kq + khalf * 512;

    // ================= interval P =================
    {
      const int layer = role >> 1, zr = role & 1;
      const bool active = layer ? (s >= 1 && s <= SEQ) : (s < SEQ);
      if (active) {
        const unsigned short *a1, *a2;
        if (layer == 0) {
          a1 = xP + (long)m * (SEQ * HID) + (long)s * HID + aoff;
          a2 = h0b + pPrev + m * HID + aoff;
        } else {
          a1 = h0b + pPrev + m * HID + aoff;
          a2 = h1b + pPrev2 + m * HID + aoff;
        }
        floatx4 acc = gpair(a1, a2, sWP, khalf, lane);
        red[wave * 64 + lane] = acc;
        __syncthreads();
        if (wave < 2) {
          floatx4 ss = red[wave * 64 + lane] + red[(wave + 2) * 64 + lane];
          int n = c0 + l15;
          float bv = ldflag(zr ? bhr : bhz, (long)layer * HID + n, flag);
          #pragma unroll
          for (int r = 0; r < 4; ++r) {
            int row = wave * 16 + (lane >> 4) * 4 + r;
            int idx = row * HID + n;
            float v = sigmoidf_(ss[r] + bv);
            if (role == 0)      GSTW(z0f + idx, v);
            else if (role == 1) GSTH(rh0 + idx, (unsigned int)f2bf(v * h0f[idx]));
            else if (role == 2) GSTW(z1f + idx, v);
            else                GSTH(rh1 + idx, (unsigned int)f2bf(v * h1f[idx]));
          }
        }
      }
    }
    bt += NBLK; gbar(barCnt, bt, blk);

    // ================= interval Q =================
    if (role == 0) {            // g0 + h0 update (step s)
      if (s < SEQ) {
        const unsigned short* a1 = xP + (long)m * (SEQ * HID) + (long)s * HID + aoff;
        const unsigned short* a2 = rh0 + m * HID + aoff;
        floatx4 acc = gpair(a1, a2, sWQ, khalf, lane);
        red[wave * 64 + lane] = acc;
        __syncthreads();
        if (wave < 2) {
          floatx4 ss = red[wave * 64 + lane] + red[(wave + 2) * 64 + lane];
          int n = c0 + l15;
          float bv = ldflag(bhg, n, flag);
          #pragma unroll
          for (int r = 0; r < 4; ++r) {
            int row = wave * 16 + (lane >> 4) * 4 + r;
            int idx = row * HID + n;
            float g = tanhf(ss[r] + bv);
            float z = z0f[idx], hp = h0f[idx];
            float hn = z * hp + (1.f - z) * g;
            GSTW(h0f + idx, hn);
            GSTH(h0b + (s & 1) * NB + idx, (unsigned int)f2bf(hn));
            if (s == SEQ - 1) outw_wt(out, flag, 16777216L + (long)row * 2048 + n, hn);
          }
        }
      }
    } else if (role == 1) {     // g1 + h1 update (step s-1)
      if (s >= 1 && s <= SEQ) {
        const unsigned short* a1 = h0b + pPrev + m * HID + aoff;
        const unsigned short* a2 = rh1 + m * HID + aoff;
        floatx4 acc = gpair(a1, a2, sWQ, khalf, lane);
        red[wave * 64 + lane] = acc;
        __syncthreads();
        if (wave < 2) {
          floatx4 ss = red[wave * 64 + lane] + red[(wave + 2) * 64 + lane];
          int n = c0 + l15;
          float bv = ldflag(bhg, (long)HID + n, flag);
          #pragma unroll
          for (int r = 0; r < 4; ++r) {
            int row = wave * 16 + (lane >> 4) * 4 + r;
            int idx = row * HID + n;
            float g = tanhf(ss[r] + bv);
            float z = z1f[idx], hp = h1f[idx];
            float hn = z * hp + (1.f - z) * g;
            GSTW(h1f + idx, hn);
            GSTH(h1b + ((s + 1) & 1) * NB + idx, (unsigned int)f2bf(hn));
            if (s == SEQ) outw_wt(out, flag, 16777216L + (long)row * 2048 + 1024 + n, hn);
          }
        }
      }
    } else if (role == 2) {     // Y_{s-2}
      if (s >= 2) {
        const int cy = (blk - 128) * 16;
        const unsigned short* a = h1b + pPrev2 + m * HID + aoff;
        floatx4 acc = gsingle(a, sWQ, khalf, lane);
        red[wave * 64 + lane] = acc;
        __syncthreads();
        if (wave < 2) {
          floatx4 ss = red[wave * 64 + lane] + red[(wave + 2) * 64 + lane];
          int n = cy + l15;
          float bv = ldflag(bY, n, flag);
          const int tY = s - 2;
          #pragma unroll
          for (int r = 0; r < 4; ++r) {
            int brow = wave * 16 + (lane >> 4) * 4 + r;
            long oidx = ((long)brow * SEQ + tY) * HID + n;
            outw_wt(out, flag, oidx, ss[r] + bv);
          }
        }
      }
    }
    bt += NBLK; gbar(barCnt, bt, blk);
  }
}

extern "C" void kernel_launch(void* const* d_in, const int* in_sizes, int n_in,
                              void* d_out, int out_size, void* d_ws, size_t ws_size,
                              hipStream_t stream) {
  const void* x   = d_in[0];
  const void* h0i = d_in[1];
  const void* Wxz = d_in[2];
  const void* Wxr = d_in[3];
  const void* Wxg = d_in[4];
  const void* Whz = d_in[5];
  const void* Whr = d_in[6];
  const void* Whg = d_in[7];
  const void* bhz = d_in[8];
  const void* bhr = d_in[9];
  const void* bhg = d_in[10];
  const void* WY  = d_in[11];
  const void* bY  = d_in[12];

  char* ws = (char*)d_ws;
  int* flag   = (int*)ws;
  int* barCnt = (int*)(ws + 1024);                    // 8 counters, 256 B apart
  float* h0f = (float*)(ws + 4096);
  float* h1f = h0f + NB;
  float* z0f = h1f + NB;
  float* z1f = z0f + NB;
  unsigned short* h0b = (unsigned short*)(z1f + NB);  // 2*NB
  unsigned short* h1b = h0b + 2 * NB;                 // 2*NB
  unsigned short* rh0 = h1b + 2 * NB;
  unsigned short* rh1 = rh0 + NB;
  unsigned short* xb  = (unsigned short*)(ws + (1 << 20));
  unsigned short* wcv = xb + 16777216L;
  unsigned short* wyc = wcv + 12582912L;

  hipMemsetAsync(barCnt, 0, 2048, stream);
  detect_k<<<1, 64, 0, stream>>>((const unsigned int*)x, flag);
  convert_k<<<2048, 256, 0, stream>>>((const float*)x,
      (const float*)Wxz, (const float*)Wxr, (const float*)Wxg,
      (const float*)Whz, (const float*)Whr, (const float*)Whg,
      (const float*)WY, xb, wcv, wyc, flag);

  static int attr_set = 0;
  if (!attr_set) {
    hipFuncSetAttribute((const void*)gru2, hipFuncAttributeMaxDynamicSharedMemorySize, 135168);
    attr_set = 1;
  }

  void* out = d_out;
  const int* flagc = flag;
  int* barc = barCnt;
  void* args[] = { (void*)&x, (void*)&h0i, (void*)&Wxz, (void*)&Wxr, (void*)&Wxg,
                   (void*)&Whz, (void*)&Whr, (void*)&Whg, (void*)&bhz, (void*)&bhr,
                   (void*)&bhg, (void*)&WY, (void*)&bY, (void*)&out, (void*)&flagc,
                   (void*)&barc, (void*)&xb, (void*)&wcv, (void*)&wyc,
                   (void*)&h0f, (void*)&h1f, (void*)&z0f, (void*)&z1f,
                   (void*)&h0b, (void*)&h1b, (void*)&rh0, (void*)&rh1 };
  hipLaunchCooperativeKernel((const void*)gru2, dim3(NBLK), dim3(256), args, 135168, stream);
}

// Round 5
// 8760.002 us; speedup vs baseline: 2.3071x; 1.5316x over previous
//
#include <hip/hip_runtime.h>
#include <hip/hip_bf16.h>

typedef __bf16 bf16x8 __attribute__((ext_vector_type(8)));
typedef float floatx4 __attribute__((ext_vector_type(4)));

#define HID 1024
#define HH (1024*1024)
#define SEQ 512
#define NB 32768  /* 32*1024 state elements */
#define NBLK 256

__device__ __forceinline__ float bf2f(unsigned short u) {
  union { unsigned int i; float f; } v; v.i = ((unsigned int)u) << 16; return v.f;
}
__device__ __forceinline__ unsigned short f2bf(float f) {
  union { float f; unsigned int i; } v; v.f = f;
  unsigned int i = v.i;
  return (unsigned short)((i + 0x7fffu + ((i >> 16) & 1u)) >> 16);
}
__device__ __forceinline__ float ldflag(const void* p, long i, int flag) {
  return flag ? ((const float*)p)[i] : bf2f(((const unsigned short*)p)[i]);
}
__device__ __forceinline__ float sigmoidf_(float x) { return 1.0f / (1.0f + __expf(-x)); }

// plain stores for state/output (round-3 proven; sc-flag experiments abandoned)
#define GSTH(p_, v_)   asm volatile("global_store_short %0, %1, off sc0 sc1" :: "v"(p_), "v"(v_) : "memory")
#define GSTW(p_, v_)   asm volatile("global_store_dword %0, %1, off sc0 sc1" :: "v"(p_), "v"(v_) : "memory")

__device__ __forceinline__ void outw_wt(void* out, int flag, long idx, float v) {
  if (flag) { GSTW((float*)out + idx, v); }
  else      { GSTH((unsigned short*)out + idx, (unsigned int)f2bf(v)); }
}

// ---- dtype detection: bf16 (flag=0) vs fp32 (flag=1) ----
__global__ void detect_k(const unsigned int* __restrict__ xw, int* __restrict__ flag) {
  unsigned int w = xw[threadIdx.x];
  int e = (w >> 7) & 0xFF;
  int ok = (e >= 100 && e <= 141) ? 1 : 0;
  unsigned long long m = __ballot(ok);
  if (threadIdx.x == 0) *flag = (__popcll(m) >= 36) ? 0 : 1;
}

// ---- fp32 -> bf16 conversion of x, 6 weight tensors, WY (no-op when flag=0) ----
__global__ void convert_k(const float* __restrict__ x,
                          const float* __restrict__ w0, const float* __restrict__ w1,
                          const float* __restrict__ w2, const float* __restrict__ w3,
                          const float* __restrict__ w4, const float* __restrict__ w5,
                          const float* __restrict__ wy,
                          unsigned short* __restrict__ xb, unsigned short* __restrict__ wc,
                          unsigned short* __restrict__ wyc, const int* __restrict__ flag) {
  if (*flag == 0) return;
  const float* Ws[6] = { w0, w1, w2, w3, w4, w5 };
  const long total = 3801088;
  for (long c = (long)blockIdx.x * 256 + threadIdx.x; c < total; c += (long)gridDim.x * 256) {
    long e = c * 8;
    const float* src; unsigned short* dst; long off;
    if (e < 16777216)      { src = x;  dst = xb;  off = e; }
    else if (e < 29360128) { long r = e - 16777216; int wi = (int)(r >> 21);
                             src = Ws[wi]; dst = wc + (long)wi * 2097152; off = r & 2097151; }
    else                   { src = wy; dst = wyc; off = e - 29360128; }
    float4 a = *(const float4*)(src + off);
    float4 b = *(const float4*)(src + off + 4);
    uint4 o;
    o.x = (unsigned)f2bf(a.x) | ((unsigned)f2bf(a.y) << 16);
    o.y = (unsigned)f2bf(a.z) | ((unsigned)f2bf(a.w) << 16);
    o.z = (unsigned)f2bf(b.x) | ((unsigned)f2bf(b.y) << 16);
    o.w = (unsigned)f2bf(b.z) | ((unsigned)f2bf(b.w) << 16);
    *(uint4*)(dst + off) = o;
  }
}

// ---- init-time grid barrier: round-3 proven (full fences per block) ----
__device__ __forceinline__ void gbar(int* cnt, int target, int blk) {
  __syncthreads();
  if (threadIdx.x == 0) {
    __builtin_amdgcn_fence(__ATOMIC_RELEASE, "agent");
    __hip_atomic_fetch_add(cnt + (blk & 7) * 64, 1, __ATOMIC_RELAXED, __HIP_MEMORY_SCOPE_AGENT);
    int ssum;
    do {
      ssum = 0;
      #pragma unroll
      for (int i = 0; i < 8; ++i)
        ssum += __hip_atomic_load(cnt + i * 64, __ATOMIC_RELAXED, __HIP_MEMORY_SCOPE_AGENT);
      if (ssum < target) __builtin_amdgcn_s_sleep(1);
    } while (ssum < target);
    __builtin_amdgcn_fence(__ATOMIC_ACQUIRE, "agent");
  }
  __syncthreads();
}

// ---- per-phase hierarchical grid barrier: one wbl2 + one L2-inv per XCD.
// All blocks on an XCD share its L2; each wave's vmcnt(0) before syncthreads
// puts its stores in L2 (write-through L1). LAST arriver per XCD executes the
// release fence (buffer_wbl2 sc1: flushes the whole XCD L2 to the coherent IF)
// then posts the XCD's block count. After the global poll, FIRST ticket-taker
// per XCD executes the acquire fence (L1+L2 inv) and posts "go"; the rest do a
// plain buffer_inv (own-CU L1 only - leader's inv doesn't reach their L1s).
__device__ __forceinline__ void gbar2(int* xcdArr, int* gCnt, int* xcdTick, int* xcdGo,
                                      int myxcd, int xcdTot, int pidx) {
  asm volatile("s_waitcnt vmcnt(0)" ::: "memory");  // this wave's stores -> L2
  __syncthreads();                                  // all waves drained
  if (threadIdx.x == 0) {
    int old = __hip_atomic_fetch_add(xcdArr + myxcd * 64, 1,
                                     __ATOMIC_RELAXED, __HIP_MEMORY_SCOPE_AGENT);
    if (old == pidx * xcdTot - 1) {                 // last arriver on this XCD
      __builtin_amdgcn_fence(__ATOMIC_RELEASE, "agent");    // wbl2 + waitcnt
      __hip_atomic_fetch_add(gCnt + myxcd * 64, xcdTot,
                             __ATOMIC_RELAXED, __HIP_MEMORY_SCOPE_AGENT);
    }
    const int target = NBLK * pidx;
    int ssum;
    do {
      ssum = 0;
      #pragma unroll
      for (int i = 0; i < 8; ++i)
        ssum += __hip_atomic_load(gCnt + i * 64, __ATOMIC_RELAXED, __HIP_MEMORY_SCOPE_AGENT);
      if (ssum < target) __builtin_amdgcn_s_sleep(1);
    } while (ssum < target);
    int t = __hip_atomic_fetch_add(xcdTick + myxcd * 64, 1,
                                   __ATOMIC_RELAXED, __HIP_MEMORY_SCOPE_AGENT);
    if (t == (pidx - 1) * xcdTot) {                 // first ticket this phase
      __builtin_amdgcn_fence(__ATOMIC_ACQUIRE, "agent");    // L1+L2 inv
      asm volatile("s_waitcnt vmcnt(0)" ::: "memory");      // inv complete
      __hip_atomic_store(xcdGo + myxcd * 64, pidx,
                         __ATOMIC_RELAXED, __HIP_MEMORY_SCOPE_AGENT);
    } else {
      while (__hip_atomic_load(xcdGo + myxcd * 64, __ATOMIC_RELAXED,
                               __HIP_MEMORY_SCOPE_AGENT) < pidx)
        __builtin_amdgcn_s_sleep(1);
      asm volatile("buffer_inv" ::: "memory");      // own-CU L1 invalidate only
    }
  }
  __syncthreads();
}

// ---- stage a (W,U) pair of 16 rows x K=1024 each into MFMA-frag-ordered LDS ----
// frag layout (ushort idx): ((m*32 + kc)*64 + L)*8, kc=k>>5, L=((k>>3)&3)*16 | row
__device__ __forceinline__ void stage2(unsigned short* dst,
                                       const unsigned short* __restrict__ s0,
                                       const unsigned short* __restrict__ s1,
                                       int n0, int tid) {
  const unsigned short* srcs[2] = { s0, s1 };
  #pragma unroll
  for (int i = 0; i < 16; ++i) {
    int idx = i * 256 + tid;          // 0..4095: 2 matrices x 16 rows x 128 k8
    int m = idx >> 11;
    int rem = idx & 2047;
    int r = rem >> 7, k8 = rem & 127;
    bf16x8 v = *(const bf16x8*)(srcs[m] + (long)(n0 + r) * HID + k8 * 8);
    int kc = k8 >> 2, L = ((k8 & 3) << 4) | r;
    *(bf16x8*)(dst + (((m * 32 + kc) * 64 + L) << 3)) = v;
  }
}
__device__ __forceinline__ void stage1(unsigned short* dst,
                                       const unsigned short* __restrict__ s0,
                                       int n0, int tid) {
  #pragma unroll
  for (int i = 0; i < 8; ++i) {
    int idx = i * 256 + tid;          // 0..2047
    int r = idx >> 7, k8 = idx & 127;
    bf16x8 v = *(const bf16x8*)(s0 + (long)(n0 + r) * HID + k8 * 8);
    int kc = k8 >> 2, L = ((k8 & 3) << 4) | r;
    *(bf16x8*)(dst + ((kc * 64 + L) << 3)) = v;
  }
}

// ---- per-wave GEMM: A from global (pre-offset), W from frag-ordered LDS ----
__device__ __forceinline__ floatx4 gpair(const unsigned short* __restrict__ a1,
                                         const unsigned short* __restrict__ a2,
                                         const unsigned short* sW, int khalf, int lane) {
  floatx4 acc = {0.f, 0.f, 0.f, 0.f};
  const unsigned short* w1 = sW + (((khalf * 16) * 64 + lane) << 3);
  const unsigned short* w2 = sW + (((32 + khalf * 16) * 64 + lane) << 3);
  #pragma unroll
  for (int j = 0; j < 16; ++j)
    acc = __builtin_amdgcn_mfma_f32_16x16x32_bf16(*(const bf16x8*)(a1 + j * 32),
                                                  *(const bf16x8*)(w1 + j * 512), acc, 0, 0, 0);
  #pragma unroll
  for (int j = 0; j < 16; ++j)
    acc = __builtin_amdgcn_mfma_f32_16x16x32_bf16(*(const bf16x8*)(a2 + j * 32),
                                                  *(const bf16x8*)(w2 + j * 512), acc, 0, 0, 0);
  return acc;
}
__device__ __forceinline__ floatx4 gsingle(const unsigned short* __restrict__ a,
                                           const unsigned short* sW, int khalf, int lane) {
  floatx4 acc = {0.f, 0.f, 0.f, 0.f};
  const unsigned short* w = sW + (((khalf * 16) * 64 + lane) << 3);
  #pragma unroll
  for (int j = 0; j < 16; ++j)
    acc = __builtin_amdgcn_mfma_f32_16x16x32_bf16(*(const bf16x8*)(a + j * 32),
                                                  *(const bf16x8*)(w + j * 512), acc, 0, 0, 0);
  return acc;
}

// Persistent GRU, 256 blocks x 256 threads, LDS-resident weights.
// P roles (blk>>6): 0=z0, 1=r0, 2=z1, 3=r1; 16 cols each ((blk&63)*16).
// Q roles: 0=g0, 1=g1, 2=Y (16 cols, (blk-128)*16), 3=idle.
__global__ void __launch_bounds__(256, 1) gru2(
    const void* __restrict__ x, const void* __restrict__ h0i,
    const void* __restrict__ Wxz, const void* __restrict__ Wxr, const void* __restrict__ Wxg,
    const void* __restrict__ Whz, const void* __restrict__ Whr, const void* __restrict__ Whg,
    const void* __restrict__ bhz, const void* __restrict__ bhr, const void* __restrict__ bhg,
    const void* __restrict__ WY, const void* __restrict__ bY,
    void* __restrict__ out, const int* __restrict__ flagp, int* __restrict__ barBase,
    const unsigned short* __restrict__ xb, const unsigned short* __restrict__ wcv,
    const unsigned short* __restrict__ wyc,
    float* __restrict__ h0f, float* __restrict__ h1f,
    float* __restrict__ z0f, float* __restrict__ z1f,
    unsigned short* __restrict__ h0b, unsigned short* __restrict__ h1b,
    unsigned short* __restrict__ rh0, unsigned short* __restrict__ rh1)
{
  extern __shared__ char smem[];
  unsigned short* sWP = (unsigned short*)smem;             // 65536 B
  unsigned short* sWQ = (unsigned short*)(smem + 65536);   // 65536 B
  floatx4* red = (floatx4*)(smem + 131072);                // 4096 B

  // counter regions, each 8 lines x 256 B
  int* barCnt   = barBase;            // init barrier
  int* xcdArr   = barBase + 512;      // per-XCD arrival
  int* gCnt     = barBase + 1024;     // global (8-way split)
  int* xcdTick  = barBase + 1536;     // per-XCD inv ticket
  int* xcdGo    = barBase + 2048;     // per-XCD go flag
  int* xcdCount = barBase + 2560;     // per-XCD block census

  const int flag = *flagp;
  const int thr  = threadIdx.x;
  const int wave = thr >> 6;
  const int lane = thr & 63;
  const int l15  = lane & 15;
  const int kq   = (lane >> 4) * 8;
  const int blk  = blockIdx.x;
  const int role = blk >> 6;
  const int c0   = (blk & 63) * 16;
  // HW_REG_XCC_ID = hwreg 20, offset 0, size 4  ->  20 | (0<<6) | ((4-1)<<11)
  const int myxcd = __builtin_amdgcn_s_getreg(20 | (3 << 11)) & 7;

  const unsigned short* xP  = flag ? xb                : (const unsigned short*)x;
  const unsigned short* Wzp = flag ? wcv + 0L*2097152  : (const unsigned short*)Wxz;
  const unsigned short* Wrp = flag ? wcv + 1L*2097152  : (const unsigned short*)Wxr;
  const unsigned short* Wgp = flag ? wcv + 2L*2097152  : (const unsigned short*)Wxg;
  const unsigned short* Uzp = flag ? wcv + 3L*2097152  : (const unsigned short*)Whz;
  const unsigned short* Urp = flag ? wcv + 4L*2097152  : (const unsigned short*)Whr;
  const unsigned short* Ugp = flag ? wcv + 5L*2097152  : (const unsigned short*)Whg;
  const unsigned short* WYp = flag ? wyc               : (const unsigned short*)WY;

  // ---- XCD census (read back after init barrier) ----
  if (thr == 0)
    __hip_atomic_fetch_add(xcdCount + myxcd * 64, 1, __ATOMIC_RELAXED, __HIP_MEMORY_SCOPE_AGENT);

  // ---- one-time weight staging into LDS (block-local) ----
  {
    long off = (role >> 1) ? (long)HH : 0;
    const unsigned short* s0 = ((role & 1) ? Wrp : Wzp) + off;
    const unsigned short* s1 = ((role & 1) ? Urp : Uzp) + off;
    stage2(sWP, s0, s1, c0, thr);
  }
  if (blk < 128)      stage2(sWQ, Wgp + (blk >= 64 ? (long)HH : 0),
                             Ugp + (blk >= 64 ? (long)HH : 0), c0, thr);
  else if (blk < 192) stage1(sWQ, WYp, (blk - 128) * 16, thr);

  // ---- init hidden state (h_{-1}) into both parity buffers ----
  {
    int gtid = blk * 256 + thr;          // 0..65535
    int layer = gtid >> 15, i = gtid & 32767;
    float v = ldflag(h0i, (long)layer * NB + i, flag);
    unsigned int b = f2bf(v);
    if (layer == 0) { GSTW(h0f + i, v); GSTH(h0b + i, b); GSTH(h0b + NB + i, b); }
    else            { GSTW(h1f + i, v); GSTH(h1b + i, b); GSTH(h1b + NB + i, b); }
  }
  asm volatile("s_waitcnt vmcnt(0)" ::: "memory");
  gbar(barCnt, NBLK, blk);               // init barrier (full fences, proven)

  int xcdTot = 0;
  if (thr == 0)
    xcdTot = __hip_atomic_load(xcdCount + myxcd * 64, __ATOMIC_RELAXED, __HIP_MEMORY_SCOPE_AGENT);
  int pidx = 0;

  for (int s = 0; s < SEQ + 2; ++s) {
    const int pPrev  = ((s + 1) & 1) * NB;  // parity slot of h_{s-1}
    const int pPrev2 = (s & 1) * NB;        // parity slot of h_{s-2}
    const int mt = wave & 1, khalf = wave >> 1;
    const int m = mt * 16 + l15;
    const int aoff = kq + khalf * 512;

    // ================= interval P =================
    {
      const int layer = role >> 1, zr = role & 1;
      const bool active = layer ? (s >= 1 && s <= SEQ) : (s < SEQ);
      if (active) {
        const unsigned short *a1, *a2;
        if (layer == 0) {
          a1 = xP + (long)m * (SEQ * HID) + (long)s * HID + aoff;
          a2 = h0b + pPrev + m * HID + aoff;
        } else {
          a1 = h0b + pPrev + m * HID + aoff;
          a2 = h1b + pPrev2 + m * HID + aoff;
        }
        floatx4 acc = gpair(a1, a2, sWP, khalf, lane);
        red[wave * 64 + lane] = acc;
        __syncthreads();
        if (wave < 2) {
          floatx4 ss = red[wave * 64 + lane] + red[(wave + 2) * 64 + lane];
          int n = c0 + l15;
          float bv = ldflag(zr ? bhr : bhz, (long)layer * HID + n, flag);
          #pragma unroll
          for (int r = 0; r < 4; ++r) {
            int row = wave * 16 + (lane >> 4) * 4 + r;
            int idx = row * HID + n;
            float v = sigmoidf_(ss[r] + bv);
            if (role == 0)      GSTW(z0f + idx, v);
            else if (role == 1) GSTH(rh0 + idx, (unsigned int)f2bf(v * h0f[idx]));
            else if (role == 2) GSTW(z1f + idx, v);
            else                GSTH(rh1 + idx, (unsigned int)f2bf(v * h1f[idx]));
          }
        }
      }
    }
    ++pidx; gbar2(xcdArr, gCnt, xcdTick, xcdGo, myxcd, xcdTot, pidx);

    // ================= interval Q =================
    if (role == 0) {            // g0 + h0 update (step s)
      if (s < SEQ) {
        const unsigned short* a1 = xP + (long)m * (SEQ * HID) + (long)s * HID + aoff;
        const unsigned short* a2 = rh0 + m * HID + aoff;
        floatx4 acc = gpair(a1, a2, sWQ, khalf, lane);
        red[wave * 64 + lane] = acc;
        __syncthreads();
        if (wave < 2) {
          floatx4 ss = red[wave * 64 + lane] + red[(wave + 2) * 64 + lane];
          int n = c0 + l15;
          float bv = ldflag(bhg, n, flag);
          #pragma unroll
          for (int r = 0; r < 4; ++r) {
            int row = wave * 16 + (lane >> 4) * 4 + r;
            int idx = row * HID + n;
            float g = tanhf(ss[r] + bv);
            float z = z0f[idx], hp = h0f[idx];
            float hn = z * hp + (1.f - z) * g;
            GSTW(h0f + idx, hn);
            GSTH(h0b + (s & 1) * NB + idx, (unsigned int)f2bf(hn));
            if (s == SEQ - 1) outw_wt(out, flag, 16777216L + (long)row * 2048 + n, hn);
          }
        }
      }
    } else if (role == 1) {     // g1 + h1 update (step s-1)
      if (s >= 1 && s <= SEQ) {
        const unsigned short* a1 = h0b + pPrev + m * HID + aoff;
        const unsigned short* a2 = rh1 + m * HID + aoff;
        floatx4 acc = gpair(a1, a2, sWQ, khalf, lane);
        red[wave * 64 + lane] = acc;
        __syncthreads();
        if (wave < 2) {
          floatx4 ss = red[wave * 64 + lane] + red[(wave + 2) * 64 + lane];
          int n = c0 + l15;
          float bv = ldflag(bhg, (long)HID + n, flag);
          #pragma unroll
          for (int r = 0; r < 4; ++r) {
            int row = wave * 16 + (lane >> 4) * 4 + r;
            int idx = row * HID + n;
            float g = tanhf(ss[r] + bv);
            float z = z1f[idx], hp = h1f[idx];
            float hn = z * hp + (1.f - z) * g;
            GSTW(h1f + idx, hn);
            GSTH(h1b + ((s + 1) & 1) * NB + idx, (unsigned int)f2bf(hn));
            if (s == SEQ) outw_wt(out, flag, 16777216L + (long)row * 2048 + 1024 + n, hn);
          }
        }
      }
    } else if (role == 2) {     // Y_{s-2}
      if (s >= 2) {
        const int cy = (blk - 128) * 16;
        const unsigned short* a = h1b + pPrev2 + m * HID + aoff;
        floatx4 acc = gsingle(a, sWQ, khalf, lane);
        red[wave * 64 + lane] = acc;
        __syncthreads();
        if (wave < 2) {
          floatx4 ss = red[wave * 64 + lane] + red[(wave + 2) * 64 + lane];
          int n = cy + l15;
          float bv = ldflag(bY, n, flag);
          const int tY = s - 2;
          #pragma unroll
          for (int r = 0; r < 4; ++r) {
            int brow = wave * 16 + (lane >> 4) * 4 + r;
            long oidx = ((long)brow * SEQ + tY) * HID + n;
            outw_wt(out, flag, oidx, ss[r] + bv);
          }
        }
      }
    }
    ++pidx; gbar2(xcdArr, gCnt, xcdTick, xcdGo, myxcd, xcdTot, pidx);
  }
}

extern "C" void kernel_launch(void* const* d_in, const int* in_sizes, int n_in,
                              void* d_out, int out_size, void* d_ws, size_t ws_size,
                              hipStream_t stream) {
  const void* x   = d_in[0];
  const void* h0i = d_in[1];
  const void* Wxz = d_in[2];
  const void* Wxr = d_in[3];
  const void* Wxg = d_in[4];
  const void* Whz = d_in[5];
  const void* Whr = d_in[6];
  const void* Whg = d_in[7];
  const void* bhz = d_in[8];
  const void* bhr = d_in[9];
  const void* bhg = d_in[10];
  const void* WY  = d_in[11];
  const void* bY  = d_in[12];

  char* ws = (char*)d_ws;
  int* flag    = (int*)ws;
  int* barBase = (int*)(ws + 1024);   // 6 regions x 8 lines x 256 B = 12288 B
  float* h0f = (float*)(ws + 16384);
  float* h1f = h0f + NB;
  float* z0f = h1f + NB;
  float* z1f = z0f + NB;
  unsigned short* h0b = (unsigned short*)(z1f + NB);  // 2*NB
  unsigned short* h1b = h0b + 2 * NB;                 // 2*NB
  unsigned short* rh0 = h1b + 2 * NB;
  unsigned short* rh1 = rh0 + NB;
  unsigned short* xb  = (unsigned short*)(ws + (1 << 20));
  unsigned short* wcv = xb + 16777216L;
  unsigned short* wyc = wcv + 12582912L;

  hipMemsetAsync(barBase, 0, 12288, stream);
  detect_k<<<1, 64, 0, stream>>>((const unsigned int*)x, flag);
  convert_k<<<2048, 256, 0, stream>>>((const float*)x,
      (const float*)Wxz, (const float*)Wxr, (const float*)Wxg,
      (const float*)Whz, (const float*)Whr, (const float*)Whg,
      (const float*)WY, xb, wcv, wyc, flag);

  static int attr_set = 0;
  if (!attr_set) {
    hipFuncSetAttribute((const void*)gru2, hipFuncAttributeMaxDynamicSharedMemorySize, 135168);
    attr_set = 1;
  }

  void* out = d_out;
  const int* flagc = flag;
  int* barc = barBase;
  void* args[] = { (void*)&x, (void*)&h0i, (void*)&Wxz, (void*)&Wxr, (void*)&Wxg,
                   (void*)&Whz, (void*)&Whr, (void*)&Whg, (void*)&bhz, (void*)&bhr,
                   (void*)&bhg, (void*)&WY, (void*)&bY, (void*)&out, (void*)&flagc,
                   (void*)&barc, (void*)&xb, (void*)&wcv, (void*)&wyc,
                   (void*)&h0f, (void*)&h1f, (void*)&z0f, (void*)&z1f,
                   (void*)&h0b, (void*)&h1b, (void*)&rh0, (void*)&rh1 };
  hipLaunchCooperativeKernel((const void*)gru2, dim3(NBLK), dim3(256), args, 135168, stream);
}